// Round 3
// baseline (10307.552 us; speedup 1.0000x reference)
//
#include <hip/hip_runtime.h>
#include <math.h>

#define NN 40
#define DD 768
#define TT 820   // (N+1)*N/2

typedef unsigned short u16;
typedef __attribute__((ext_vector_type(8))) short bfrag8;
typedef __attribute__((ext_vector_type(4))) float facc4;

__device__ __forceinline__ int ftd(int b, int e) {
    int l = e - b;
    return TT - (NN - l + 2) * (NN - l + 1) / 2 + b;
}
__device__ __forceinline__ float bf2f(u16 u) {
    union { unsigned int i; float f; } x; x.i = ((unsigned)u) << 16; return x.f;
}
__device__ __forceinline__ u16 f2bf(float f) {
    unsigned u = __float_as_uint(f);
    u += 0x7fff + ((u >> 16) & 1);
    return (u16)(u >> 16);
}
__device__ __forceinline__ float dot2(unsigned a, unsigned c) {
    return bf2f((u16)a) * bf2f((u16)c) + bf2f((u16)(a >> 16)) * bf2f((u16)(c >> 16));
}

#define GLOAD16(gp, lp) __builtin_amdgcn_global_load_lds( \
    (const __attribute__((address_space(1))) unsigned int*)(gp), \
    (__attribute__((address_space(3))) unsigned int*)(lp), 16, 0, 0)

#define MODE_CONTIG 0
#define MODE_IN 1
#define MODE_OUT 2
// EPI: 0 = plain bf16 store, 1 = relu(+bias) (h1), 2 = w*relu(+bias) (v)

// C[m][n] = sum_k A[m][k] * W[n][k]  (A gathered bf16 rows, W row-major [N][KDIM] bf16)
// m97 structure: 128x128 tile, BK=32, 4 waves (2x2), each wave 64x64 = 4x4 frags 16x16x32
template<int MODE, int KDIM, int EPI>
__global__ __launch_bounds__(256)
void mgemm(const u16* __restrict__ Abase,
           const u16* __restrict__ ivb, const u16* __restrict__ ovb,
           const u16* __restrict__ W, const float* __restrict__ bias,
           const float* __restrict__ wbuf, u16* __restrict__ Out,
           int M, int level, int g0, int Sps)
{
    __shared__ __align__(16) u16 As[128 * 32];   // 8 KB
    __shared__ __align__(16) u16 Bs[128 * 32];   // 8 KB
    const int tid = threadIdx.x;
    const int lane = tid & 63;
    const int wv = tid >> 6;
    const int m0 = blockIdx.x * 128;
    const int j0 = blockIdx.y * 128;

    const int srow = tid >> 2;          // 0..63 staging row
    const int ko = (tid & 3) * 8;       // staging k-offset (elements)

    const u16 *a0p0, *a0p1, *a1p0, *a1p1;
    {
        int arow = m0 + srow; if (arow >= M) arow = M - 1;
        int brow = m0 + srow + 64; if (brow >= M) brow = M - 1;
        int rows[2] = {arow, brow};
        const u16* P0[2]; const u16* P1[2];
        #pragma unroll
        for (int t = 0; t < 2; ++t) {
            int r = rows[t];
            if (MODE == MODE_CONTIG) {
                P0[t] = Abase + (size_t)r * KDIM + ko; P1[t] = P0[t];
            } else {
                int p = r >> 5, bb = r & 31;
                int g = g0 + p / Sps, si = p % Sps;
                if (MODE == MODE_IN) {
                    int s = si + 1;
                    P0[t] = ivb + (size_t)(ftd(g, g + s) * 32 + bb) * DD + ko;
                    P1[t] = ivb + (size_t)(ftd(g + s, g + level) * 32 + bb) * DD + ko;
                } else {
                    int pc, scl;
                    if (si < g) { pc = ftd(si, g + level); scl = ftd(si, g); }
                    else { int c = si + level + 1; pc = ftd(g, c); scl = ftd(g + level, c); }
                    P0[t] = ovb + (size_t)(pc * 32 + bb) * DD + ko;
                    P1[t] = ivb + (size_t)(scl * 32 + bb) * DD + ko;
                }
            }
        }
        a0p0 = P0[0]; a0p1 = P1[0]; a1p0 = P0[1]; a1p1 = P1[1];
    }
    const u16* bq0 = W + (size_t)(j0 + srow) * KDIM + ko;
    const u16* bq1 = bq0 + (size_t)64 * KDIM;

    u16* AsW0 = As + wv * 512;          // wave-uniform dests, lanes write 16B linear
    u16* AsW1 = As + 2048 + wv * 512;
    u16* BsW0 = Bs + wv * 512;
    u16* BsW1 = Bs + 2048 + wv * 512;

    facc4 acc[4][4];
    #pragma unroll
    for (int i = 0; i < 4; ++i)
        #pragma unroll
        for (int j = 0; j < 4; ++j)
            acc[i][j] = (facc4){0.f, 0.f, 0.f, 0.f};

    const int wr = wv >> 1, wc = wv & 1;
    const int fr = lane & 15, fk = (lane >> 4) * 8;

    for (int k0 = 0; k0 < KDIM; k0 += 32) {
        const u16 *sa0, *sa1;
        if (MODE == MODE_CONTIG) { sa0 = a0p0 + k0; sa1 = a1p0 + k0; }
        else {
            sa0 = (k0 < DD) ? (a0p0 + k0) : (a0p1 + (k0 - DD));
            sa1 = (k0 < DD) ? (a1p0 + k0) : (a1p1 + (k0 - DD));
        }
        GLOAD16(sa0, AsW0);
        GLOAD16(sa1, AsW1);
        GLOAD16(bq0 + k0, BsW0);
        GLOAD16(bq1 + k0, BsW1);
        __syncthreads();
        bfrag8 a[4], b[4];
        #pragma unroll
        for (int fi = 0; fi < 4; ++fi)
            a[fi] = *(const bfrag8*)&As[(wr * 64 + fi * 16 + fr) * 32 + fk];
        #pragma unroll
        for (int fj = 0; fj < 4; ++fj)
            b[fj] = *(const bfrag8*)&Bs[(wc * 64 + fj * 16 + fr) * 32 + fk];
        #pragma unroll
        for (int fi = 0; fi < 4; ++fi)
            #pragma unroll
            for (int fj = 0; fj < 4; ++fj)
                acc[fi][fj] = __builtin_amdgcn_mfma_f32_16x16x32_bf16(
                    a[fi], b[fj], acc[fi][fj], 0, 0, 0);
        __syncthreads();
    }

    const int r0 = (lane >> 4) * 4;
    #pragma unroll
    for (int fi = 0; fi < 4; ++fi) {
        #pragma unroll
        for (int r = 0; r < 4; ++r) {
            int m = m0 + wr * 64 + fi * 16 + r0 + r;
            if (m < M) {
                float wt = (EPI == 2) ? wbuf[m] : 0.f;
                #pragma unroll
                for (int fj = 0; fj < 4; ++fj) {
                    int n = j0 + wc * 64 + fj * 16 + fr;
                    float v = acc[fi][fj][r];
                    if (EPI >= 1) v = fmaxf(v + bias[n], 0.f);
                    if (EPI == 2) v *= wt;
                    Out[(size_t)m * DD + n] = f2bf(v);
                }
            }
        }
    }
}

// reduce over splits: chart[cellrow0 + gl*32+bb][col] = sum_s v[(gl*S+s)*32+bb][col]
__global__ __launch_bounds__(256)
void reduce_k(const u16* __restrict__ v, u16* __restrict__ chart,
              int cellrow0, int gc, int Sps)
{
    int idx = blockIdx.x * 256 + threadIdx.x;
    if (idx >= gc * 32 * DD) return;
    int col = idx % DD, row = idx / DD;
    int gl = row >> 5, bb = row & 31;
    float s = 0.f;
    const u16* p = v + ((size_t)(gl * Sps) * 32 + bb) * DD + col;
    for (int si = 0; si < Sps; ++si) s += bf2f(p[(size_t)si * 32 * DD]);
    chart[(size_t)(cellrow0 + row) * DD + col] = f2bf(s);
}

// fused score + softmax: one wave per (gl, bb) over the WHOLE level.
// loop over splits computing bilinear dot + child scores, then lane-parallel softmax.
template<bool INSIDE>
__global__ __launch_bounds__(256)
void scoresm_k(const u16* __restrict__ ivb, const u16* __restrict__ ivWb,
               const u16* __restrict__ ovb, float* __restrict__ isc,
               float* __restrict__ osc, float* __restrict__ wbuf,
               int level, int nb, int Sps, int cellrow0)
{
    __shared__ float sS[4][64];
    int wid = (blockIdx.x * 256 + threadIdx.x) >> 6;
    int lane = threadIdx.x & 63;
    int wv = threadIdx.x >> 6;
    if (wid >= nb * 32) return;
    int gl = wid >> 5, bb = wid & 31;
    float mx = -3.0e38f;
    for (int si = 0; si < Sps; ++si) {
        const u16 *lp, *rp; float add;
        if (INSIDE) {
            int s = si + 1;
            int lc = ftd(gl, gl + s), rc = ftd(gl + s, gl + level);
            lp = ivb + (size_t)(lc * 32 + bb) * DD;
            rp = ivWb + (size_t)(rc * 32 + bb) * DD;
            add = isc[lc * 32 + bb] + isc[rc * 32 + bb];
        } else {
            int pc, scl;
            if (si < gl) { pc = ftd(si, gl + level); scl = ftd(si, gl); }
            else { int c = si + level + 1; pc = ftd(gl, c); scl = ftd(gl + level, c); }
            lp = ovb + (size_t)(pc * 32 + bb) * DD;
            rp = ivWb + (size_t)(scl * 32 + bb) * DD;
            add = osc[pc * 32 + bb] + isc[scl * 32 + bb];
        }
        float sum = 0.f;
        #pragma unroll
        for (int i = 0; i < 3; ++i) {
            uint2 a = *(const uint2*)(lp + i * 256 + lane * 4);
            uint2 c = *(const uint2*)(rp + i * 256 + lane * 4);
            sum += dot2(a.x, c.x) + dot2(a.y, c.y);
        }
        #pragma unroll
        for (int off = 32; off; off >>= 1) sum += __shfl_xor(sum, off);
        float sc = sum + add;
        mx = fmaxf(mx, sc);
        if (lane == 0) sS[wv][si] = sc;
    }
    bool act = lane < Sps;
    float x = act ? sS[wv][lane] : -3.0e38f;
    float e = act ? expf(x - mx) : 0.f;
    float ssum = e;
    #pragma unroll
    for (int off = 32; off; off >>= 1) ssum += __shfl_xor(ssum, off);
    float wt = e / ssum;
    if (act) wbuf[(gl * Sps + lane) * 32 + bb] = wt;
    float ws = act ? wt * x : 0.f;
    #pragma unroll
    for (int off = 32; off; off >>= 1) ws += __shfl_xor(ws, off);
    if (lane == 0) {
        float* scout = INSIDE ? isc : osc;
        scout[cellrow0 + gl * 32 + bb] = ws;
    }
}

__global__ __launch_bounds__(256)
void loss_part(const u16* __restrict__ ovb, const float* __restrict__ base,
               float* __restrict__ lb)
{
    int wid = (blockIdx.x * 256 + threadIdx.x) >> 6;
    int lane = threadIdx.x & 63;
    if (wid >= NN * 32) return;
    const u16* t = ovb + (size_t)wid * DD;
    const float* b = base + (size_t)wid * DD;
    float num = 0, nt = 0, nb = 0;
    #pragma unroll
    for (int i = 0; i < 3; ++i) {
        uint2 a2 = *(const uint2*)(t + i * 256 + lane * 4);
        float4 c = *(const float4*)(b + i * 256 + lane * 4);
        float a0 = bf2f((u16)a2.x), a1 = bf2f((u16)(a2.x >> 16));
        float a2f = bf2f((u16)a2.y), a3 = bf2f((u16)(a2.y >> 16));
        num += a0 * c.x + a1 * c.y + a2f * c.z + a3 * c.w;
        nt  += a0 * a0 + a1 * a1 + a2f * a2f + a3 * a3;
        nb  += c.x * c.x + c.y * c.y + c.z * c.z + c.w * c.w;
    }
    #pragma unroll
    for (int off = 32; off; off >>= 1) {
        num += __shfl_down(num, off);
        nt  += __shfl_down(nt, off);
        nb  += __shfl_down(nb, off);
    }
    if (lane == 0) {
        float den = fmaxf(sqrtf(nt) * sqrtf(nb), 1e-8f);
        lb[wid] = 1.f - num / den;
    }
}

__global__ void loss_fin(const float* __restrict__ lb, float* __restrict__ out)
{
    __shared__ float red[256];
    float s = 0;
    for (int i = threadIdx.x; i < NN * 32; i += 256) s += lb[i];
    red[threadIdx.x] = s;
    __syncthreads();
    for (int o = 128; o; o >>= 1) {
        if (threadIdx.x < o) red[threadIdx.x] += red[threadIdx.x + o];
        __syncthreads();
    }
    if (threadIdx.x == 0) out[0] = red[0] / (NN * 32.f);
}

__global__ void cvt_k(const float* __restrict__ in, u16* __restrict__ out, int n)
{
    int idx = blockIdx.x * 256 + threadIdx.x;
    if (idx < n) out[idx] = f2bf(in[idx]);
}

__global__ void init_rootb(u16* __restrict__ ovb, const float* __restrict__ rb)
{
    int idx = blockIdx.x * 256 + threadIdx.x;
    if (idx < 32 * DD) ovb[(size_t)819 * 32 * DD + idx] = f2bf(rb[idx % DD]);
}

extern "C" void kernel_launch(void* const* d_in, const int* in_sizes, int n_in,
                              void* d_out, int out_size, void* d_ws, size_t ws_size,
                              hipStream_t stream)
{
    const float* base  = (const float*)d_in[0];
    const float* Wbil  = (const float*)d_in[1];
    const float* W1    = (const float*)d_in[2];
    const float* b1    = (const float*)d_in[3];
    const float* W2    = (const float*)d_in[4];
    const float* b2    = (const float*)d_in[5];
    const float* rbias = (const float*)d_in[6];
    float* out = (float*)d_out;

    char* ws = (char*)d_ws;
    size_t off = 0;
    auto alloc = [&](size_t bytes) { size_t o = off; off = (off + bytes + 255) & ~(size_t)255; return o; };
    const size_t SB = (size_t)TT * 32 * DD * 2;          // bf16 chart
    u16*  ivb  = (u16*)(ws + alloc(SB));
    u16*  ivWb = (u16*)(ws + alloc(SB));
    u16*  ovb  = (u16*)(ws + alloc(SB));
    u16*  W1b  = (u16*)(ws + alloc((size_t)DD * 2 * DD * 2));
    u16*  W2b  = (u16*)(ws + alloc((size_t)DD * DD * 2));
    u16*  Wbb  = (u16*)(ws + alloc((size_t)DD * DD * 2));
    float* isc = (float*)(ws + alloc((size_t)TT * 32 * 4));
    float* osc = (float*)(ws + alloc((size_t)TT * 32 * 4));
    float* wb  = (float*)(ws + alloc((size_t)1560 * 32 * 4));
    float* lb  = (float*)(ws + alloc((size_t)NN * 32 * 4));
    size_t remaining = (ws_size > off) ? (ws_size - off) : 0;

    // --- init ---
    hipMemsetAsync(isc, 0, (size_t)TT * 32 * 4 * 2 + 512, stream); // isc+osc adjacent
    cvt_k<<<(DD * 2 * DD + 255) / 256, 256, 0, stream>>>(W1, W1b, DD * 2 * DD);
    cvt_k<<<(DD * DD + 255) / 256, 256, 0, stream>>>(W2, W2b, DD * DD);
    cvt_k<<<(DD * DD + 255) / 256, 256, 0, stream>>>(Wbil, Wbb, DD * DD);
    cvt_k<<<(NN * 32 * DD + 255) / 256, 256, 0, stream>>>(base, ivb, NN * 32 * DD);
    init_rootb<<<(32 * DD + 255) / 256, 256, 0, stream>>>(ovb, rbias);
    {   // leaf ivW
        int M = NN * 32;
        dim3 g((M + 127) / 128, DD / 128);
        mgemm<MODE_CONTIG, DD, 0><<<g, 256, 0, stream>>>(
            ivb, nullptr, nullptr, Wbb, nullptr, nullptr, ivWb, M, 0, 0, 1);
    }

    for (int pass = 0; pass < 2; ++pass) {
        const bool inside = (pass == 0);
        for (int li = 0; li < (inside ? 39 : 39); ++li) {
            int L = inside ? (li + 2) : (39 - li);
            int S = inside ? (L - 1) : (NN - L);
            int nb = NN + 1 - L;
            int cellbase = TT - (NN - L + 2) * (NN - L + 1) / 2;

            if (inside)
                scoresm_k<true><<<(nb * 32 + 3) / 4, 256, 0, stream>>>(
                    ivb, ivWb, ovb, isc, osc, wb, L, nb, S, cellbase * 32);
            else
                scoresm_k<false><<<(nb * 32 + 3) / 4, 256, 0, stream>>>(
                    ivb, ivWb, ovb, isc, osc, wb, L, nb, S, cellbase * 32);

            size_t perH = (size_t)S * 32 * (2 * DD) * 2;   // h1 bytes per begin
            size_t perV = (size_t)S * 32 * DD * 2;         // v  bytes per begin
            int GC = (remaining >= perH + perV) ? (int)(remaining / (perH + perV)) : 1;
            if (GC < 1) GC = 1;
            if (GC > nb) GC = nb;
            u16* h1b = (u16*)(ws + off);
            u16* vb  = (u16*)(ws + off + (size_t)GC * perH);

            for (int g0 = 0; g0 < nb; g0 += GC) {
                int gc = (g0 + GC <= nb) ? GC : (nb - g0);
                int Mc = gc * S * 32;
                dim3 g1((Mc + 127) / 128, DD / 128);
                if (inside)
                    mgemm<MODE_IN, 2 * DD, 1><<<g1, 256, 0, stream>>>(
                        nullptr, ivb, ovb, W1b, b1, nullptr, h1b, Mc, L, g0, S);
                else
                    mgemm<MODE_OUT, 2 * DD, 1><<<g1, 256, 0, stream>>>(
                        nullptr, ivb, ovb, W1b, b1, nullptr, h1b, Mc, L, g0, S);
                mgemm<MODE_CONTIG, DD, 2><<<g1, 256, 0, stream>>>(
                    h1b, nullptr, nullptr, W2b, b2, wb + (size_t)g0 * S * 32, vb,
                    Mc, 0, 0, 1);
                reduce_k<<<(gc * 32 * DD + 255) / 256, 256, 0, stream>>>(
                    vb, inside ? ivb : ovb, (cellbase + g0) * 32, gc, S);
            }
            if (inside) {   // ivW for this level's new cells
                int M = nb * 32;
                dim3 g((M + 127) / 128, DD / 128);
                mgemm<MODE_CONTIG, DD, 0><<<g, 256, 0, stream>>>(
                    ivb + (size_t)cellbase * 32 * DD, nullptr, nullptr, Wbb, nullptr,
                    nullptr, ivWb + (size_t)cellbase * 32 * DD, M, 0, 0, 1);
            }
        }
    }

    // --- loss ---
    loss_part<<<(NN * 32 + 3) / 4, 256, 0, stream>>>(ovb, base, lb);
    loss_fin<<<1, 256, 0, stream>>>(lb, out);
}

// Round 4
// 7876.612 us; speedup vs baseline: 1.3086x; 1.3086x over previous
//
#include <hip/hip_runtime.h>
#include <math.h>

#define NN 40
#define DD 768
#define TT 820   // (N+1)*N/2

typedef unsigned short u16;
typedef __attribute__((ext_vector_type(8))) short bfrag8;
typedef __attribute__((ext_vector_type(4))) float facc4;

__device__ __forceinline__ int ftd(int b, int e) {
    int l = e - b;
    return TT - (NN - l + 2) * (NN - l + 1) / 2 + b;
}
__device__ __forceinline__ float bf2f(u16 u) {
    union { unsigned int i; float f; } x; x.i = ((unsigned)u) << 16; return x.f;
}
__device__ __forceinline__ u16 f2bf(float f) {
    unsigned u = __float_as_uint(f);
    u += 0x7fff + ((u >> 16) & 1);
    return (u16)(u >> 16);
}
__device__ __forceinline__ float dot2(unsigned a, unsigned c) {
    return bf2f((u16)a) * bf2f((u16)c) + bf2f((u16)(a >> 16)) * bf2f((u16)(c >> 16));
}

#define GLOAD16(gp, lp) __builtin_amdgcn_global_load_lds( \
    (const __attribute__((address_space(1))) unsigned int*)(gp), \
    (__attribute__((address_space(3))) unsigned int*)(lp), 16, 0, 0)

#define MODE_IN 1
#define MODE_OUT 2

// ---------------- transform: Out{U,V,W}[m][0..767] = A[m] @ Wcat-slab^T ----------------
// A: bf16 [M][768] contiguous. Wcat: [NSLAB*768][768] row-major bf16.
// grid.y = NSLAB*6; slab = blockIdx.y/6 selects output array + weight row block.
__global__ __launch_bounds__(256)
void transform_k(const u16* __restrict__ A, const u16* __restrict__ Wcat,
                 u16* __restrict__ OutU, u16* __restrict__ OutV,
                 u16* __restrict__ OutW, int M)
{
    __shared__ __align__(16) u16 As[128 * 32];
    __shared__ __align__(16) u16 Bs[128 * 32];
    const int tid = threadIdx.x, lane = tid & 63, wv = tid >> 6;
    const int m0 = blockIdx.x * 128;
    const int slab = blockIdx.y / 6;
    const int j0 = (blockIdx.y % 6) * 128;
    u16* Out = (slab == 0) ? OutU : (slab == 1 ? OutV : OutW);

    const int srow = tid >> 2;
    const int ko = (tid & 3) * 8;
    int ar0 = m0 + srow; if (ar0 >= M) ar0 = M - 1;
    int ar1 = m0 + srow + 64; if (ar1 >= M) ar1 = M - 1;
    const u16* ap0 = A + (size_t)ar0 * DD + ko;
    const u16* ap1 = A + (size_t)ar1 * DD + ko;
    const u16* bq0 = Wcat + (size_t)(slab * DD + j0 + srow) * DD + ko;
    const u16* bq1 = bq0 + (size_t)64 * DD;
    u16* AsW0 = As + wv * 512;  u16* AsW1 = As + 2048 + wv * 512;
    u16* BsW0 = Bs + wv * 512;  u16* BsW1 = Bs + 2048 + wv * 512;

    facc4 acc[4][4];
    #pragma unroll
    for (int i = 0; i < 4; ++i)
        #pragma unroll
        for (int j = 0; j < 4; ++j) acc[i][j] = (facc4){0.f, 0.f, 0.f, 0.f};

    const int wr = wv >> 1, wc = wv & 1;
    const int fr = lane & 15, fk = (lane >> 4) * 8;

    for (int k0 = 0; k0 < DD; k0 += 32) {
        GLOAD16(ap0 + k0, AsW0);
        GLOAD16(ap1 + k0, AsW1);
        GLOAD16(bq0 + k0, BsW0);
        GLOAD16(bq1 + k0, BsW1);
        __syncthreads();
        bfrag8 a[4], b[4];
        #pragma unroll
        for (int fi = 0; fi < 4; ++fi)
            a[fi] = *(const bfrag8*)&As[(wr * 64 + fi * 16 + fr) * 32 + fk];
        #pragma unroll
        for (int fj = 0; fj < 4; ++fj)
            b[fj] = *(const bfrag8*)&Bs[(wc * 64 + fj * 16 + fr) * 32 + fk];
        #pragma unroll
        for (int fi = 0; fi < 4; ++fi)
            #pragma unroll
            for (int fj = 0; fj < 4; ++fj)
                acc[fi][fj] = __builtin_amdgcn_mfma_f32_16x16x32_bf16(
                    a[fi], b[fj], acc[fi][fj], 0, 0, 0);
        __syncthreads();
    }

    const int r0l = (lane >> 4) * 4;
    #pragma unroll
    for (int fi = 0; fi < 4; ++fi)
        #pragma unroll
        for (int r = 0; r < 4; ++r) {
            int m = m0 + wr * 64 + fi * 16 + r0l + r;
            if (m < M) {
                #pragma unroll
                for (int fj = 0; fj < 4; ++fj) {
                    int n = j0 + wc * 64 + fj * 16 + fr;
                    Out[(size_t)m * DD + n] = f2bf(acc[fi][fj][r]);
                }
            }
        }
}

// ---------------- fused GEMM2: A row = relu(u_l + v_r + b1) built in-reg ----------------
// Out[m][n] = wbuf[m] * relu( sum_k A[m][k]*W2[n][k] + b2[n] )
template<int MODE>
__global__ __launch_bounds__(256)
void gemm2f_k(const u16* __restrict__ Ubase, const u16* __restrict__ Vbase,
              const u16* __restrict__ W2, const float* __restrict__ b1,
              const float* __restrict__ b2, const float* __restrict__ wbuf,
              u16* __restrict__ Out, int M, int level, int g0, int Sps)
{
    __shared__ __align__(16) u16 As[128 * 32];
    __shared__ __align__(16) u16 Bs[128 * 32];
    const int tid = threadIdx.x, lane = tid & 63, wv = tid >> 6;
    const int m0 = blockIdx.x * 128;
    const int j0 = blockIdx.y * 128;

    const int srow = tid >> 2;
    const int ko = (tid & 3) * 8;

    const u16 *u0, *v0, *u1, *v1;
    {
        int rows[2];
        rows[0] = m0 + srow; if (rows[0] >= M) rows[0] = M - 1;
        rows[1] = m0 + srow + 64; if (rows[1] >= M) rows[1] = M - 1;
        const u16* UP[2]; const u16* VP[2];
        #pragma unroll
        for (int t = 0; t < 2; ++t) {
            int r = rows[t];
            int p = r >> 5, bb = r & 31;
            int g = g0 + p / Sps, si = p % Sps;
            int uc, vc;
            if (MODE == MODE_IN) {
                int s = si + 1;
                uc = ftd(g, g + s); vc = ftd(g + s, g + level);
            } else {
                if (si < g) { uc = ftd(si, g + level); vc = ftd(si, g); }
                else { int c = si + level + 1; uc = ftd(g, c); vc = ftd(g + level, c); }
            }
            UP[t] = Ubase + (size_t)(uc * 32 + bb) * DD + ko;
            VP[t] = Vbase + (size_t)(vc * 32 + bb) * DD + ko;
        }
        u0 = UP[0]; v0 = VP[0]; u1 = UP[1]; v1 = VP[1];
    }
    const u16* bq0 = W2 + (size_t)(j0 + srow) * DD + ko;
    const u16* bq1 = bq0 + (size_t)64 * DD;
    u16* BsW0 = Bs + wv * 512;  u16* BsW1 = Bs + 2048 + wv * 512;

    facc4 acc[4][4];
    #pragma unroll
    for (int i = 0; i < 4; ++i)
        #pragma unroll
        for (int j = 0; j < 4; ++j) acc[i][j] = (facc4){0.f, 0.f, 0.f, 0.f};

    const int wr = wv >> 1, wc = wv & 1;
    const int fr = lane & 15, fk = (lane >> 4) * 8;

    for (int k0 = 0; k0 < DD; k0 += 32) {
        // B: direct global->LDS
        GLOAD16(bq0 + k0, BsW0);
        GLOAD16(bq1 + k0, BsW1);
        // A: fused reg staging, relu(u+v+b1) -> bf16 -> LDS
        float4 bia0 = *(const float4*)(b1 + k0 + ko);
        float4 bia1 = *(const float4*)(b1 + k0 + ko + 4);
        float bl[8] = {bia0.x, bia0.y, bia0.z, bia0.w, bia1.x, bia1.y, bia1.z, bia1.w};
        #pragma unroll
        for (int t = 0; t < 2; ++t) {
            const u16* up = t ? u1 : u0;
            const u16* vp = t ? v1 : v0;
            bfrag8 uu = *(const bfrag8*)(up + k0);
            bfrag8 vv = *(const bfrag8*)(vp + k0);
            bfrag8 hh;
            #pragma unroll
            for (int j = 0; j < 8; ++j) {
                float f = bf2f((u16)uu[j]) + bf2f((u16)vv[j]) + bl[j];
                hh[j] = (short)f2bf(fmaxf(f, 0.f));
            }
            *(bfrag8*)&As[(srow + t * 64) * 32 + ko] = hh;
        }
        __syncthreads();
        bfrag8 a[4], b[4];
        #pragma unroll
        for (int fi = 0; fi < 4; ++fi)
            a[fi] = *(const bfrag8*)&As[(wr * 64 + fi * 16 + fr) * 32 + fk];
        #pragma unroll
        for (int fj = 0; fj < 4; ++fj)
            b[fj] = *(const bfrag8*)&Bs[(wc * 64 + fj * 16 + fr) * 32 + fk];
        #pragma unroll
        for (int fi = 0; fi < 4; ++fi)
            #pragma unroll
            for (int fj = 0; fj < 4; ++fj)
                acc[fi][fj] = __builtin_amdgcn_mfma_f32_16x16x32_bf16(
                    a[fi], b[fj], acc[fi][fj], 0, 0, 0);
        __syncthreads();
    }

    const int r0l = (lane >> 4) * 4;
    #pragma unroll
    for (int fi = 0; fi < 4; ++fi)
        #pragma unroll
        for (int r = 0; r < 4; ++r) {
            int m = m0 + wr * 64 + fi * 16 + r0l + r;
            if (m < M) {
                float wt = wbuf[m];
                #pragma unroll
                for (int fj = 0; fj < 4; ++fj) {
                    int n = j0 + wc * 64 + fj * 16 + fr;
                    float v = fmaxf(acc[fi][fj][r] + b2[n], 0.f) * wt;
                    Out[(size_t)m * DD + n] = f2bf(v);
                }
            }
        }
}

// ---------------- reduce over splits ----------------
__global__ __launch_bounds__(256)
void reduce_k(const u16* __restrict__ v, u16* __restrict__ chart,
              int cellrow0, int gc, int Sps)
{
    int idx = blockIdx.x * 256 + threadIdx.x;
    if (idx >= gc * 32 * DD) return;
    int col = idx % DD, row = idx / DD;
    int gl = row >> 5, bb = row & 31;
    float s = 0.f;
    const u16* p = v + ((size_t)(gl * Sps) * 32 + bb) * DD + col;
    for (int si = 0; si < Sps; ++si) s += bf2f(p[(size_t)si * 32 * DD]);
    chart[(size_t)(cellrow0 + row) * DD + col] = f2bf(s);
}

// ---------------- score: one wave per (pair, bb) ----------------
template<bool INSIDE>
__global__ __launch_bounds__(256)
void score_k(const u16* __restrict__ ivb, const u16* __restrict__ IWb,
             const u16* __restrict__ ovb, const float* __restrict__ isc,
             const float* __restrict__ osc, float* __restrict__ sc,
             int level, int Pc, int Sps)
{
    int wid = (blockIdx.x * 256 + threadIdx.x) >> 6;
    int lane = threadIdx.x & 63;
    if (wid >= Pc * 32) return;
    int p = wid >> 5, bb = wid & 31;
    int g = p / Sps, si = p % Sps;
    const u16 *lp, *rp; float add;
    if (INSIDE) {
        int s = si + 1;
        int lc = ftd(g, g + s), rc = ftd(g + s, g + level);
        lp = ivb + (size_t)(lc * 32 + bb) * DD;
        rp = IWb + (size_t)(rc * 32 + bb) * DD;
        add = isc[lc * 32 + bb] + isc[rc * 32 + bb];
    } else {
        int pc, scl;
        if (si < g) { pc = ftd(si, g + level); scl = ftd(si, g); }
        else { int c = si + level + 1; pc = ftd(g, c); scl = ftd(g + level, c); }
        lp = ovb + (size_t)(pc * 32 + bb) * DD;
        rp = IWb + (size_t)(scl * 32 + bb) * DD;
        add = osc[pc * 32 + bb] + isc[scl * 32 + bb];
    }
    float sum = 0.f;
    #pragma unroll
    for (int i = 0; i < 3; ++i) {
        uint2 a = *(const uint2*)(lp + i * 256 + lane * 4);
        uint2 c = *(const uint2*)(rp + i * 256 + lane * 4);
        sum += dot2(a.x, c.x) + dot2(a.y, c.y);
    }
    #pragma unroll
    for (int off = 32; off; off >>= 1) sum += __shfl_down(sum, off);
    if (lane == 0) sc[p * 32 + bb] = sum + add;
}

// ---------------- softmax over splits ----------------
__global__ __launch_bounds__(256)
void softmax_k(const float* __restrict__ sc, float* __restrict__ wbuf,
               float* __restrict__ scout, int cellrow0, int gc, int Sps)
{
    int wid = (blockIdx.x * 256 + threadIdx.x) >> 6;
    int lane = threadIdx.x & 63;
    if (wid >= gc * 32) return;
    int gl = wid >> 5, bb = wid & 31;
    bool act = lane < Sps;
    float x = act ? sc[(gl * Sps + lane) * 32 + bb] : -3.0e38f;
    float m = x;
    #pragma unroll
    for (int off = 32; off; off >>= 1) m = fmaxf(m, __shfl_xor(m, off));
    float e = act ? expf(x - m) : 0.f;
    float ssum = e;
    #pragma unroll
    for (int off = 32; off; off >>= 1) ssum += __shfl_xor(ssum, off);
    float wt = e / ssum;
    if (act) wbuf[(gl * Sps + lane) * 32 + bb] = wt;
    float ws = act ? wt * x : 0.f;
    #pragma unroll
    for (int off = 32; off; off >>= 1) ws += __shfl_xor(ws, off);
    if (lane == 0) scout[cellrow0 + gl * 32 + bb] = ws;
}

// ---------------- loss ----------------
__global__ __launch_bounds__(256)
void loss_part(const u16* __restrict__ ovb, const float* __restrict__ base,
               float* __restrict__ lb)
{
    int wid = (blockIdx.x * 256 + threadIdx.x) >> 6;
    int lane = threadIdx.x & 63;
    if (wid >= NN * 32) return;
    const u16* t = ovb + (size_t)wid * DD;
    const float* b = base + (size_t)wid * DD;
    float num = 0, nt = 0, nb = 0;
    #pragma unroll
    for (int i = 0; i < 3; ++i) {
        uint2 a2 = *(const uint2*)(t + i * 256 + lane * 4);
        float4 c = *(const float4*)(b + i * 256 + lane * 4);
        float a0 = bf2f((u16)a2.x), a1 = bf2f((u16)(a2.x >> 16));
        float a2f = bf2f((u16)a2.y), a3 = bf2f((u16)(a2.y >> 16));
        num += a0 * c.x + a1 * c.y + a2f * c.z + a3 * c.w;
        nt  += a0 * a0 + a1 * a1 + a2f * a2f + a3 * a3;
        nb  += c.x * c.x + c.y * c.y + c.z * c.z + c.w * c.w;
    }
    #pragma unroll
    for (int off = 32; off; off >>= 1) {
        num += __shfl_down(num, off);
        nt  += __shfl_down(nt, off);
        nb  += __shfl_down(nb, off);
    }
    if (lane == 0) {
        float den = fmaxf(sqrtf(nt) * sqrtf(nb), 1e-8f);
        lb[wid] = 1.f - num / den;
    }
}

__global__ void loss_fin(const float* __restrict__ lb, float* __restrict__ out)
{
    __shared__ float red[256];
    float s = 0;
    for (int i = threadIdx.x; i < NN * 32; i += 256) s += lb[i];
    red[threadIdx.x] = s;
    __syncthreads();
    for (int o = 128; o; o >>= 1) {
        if (threadIdx.x < o) red[threadIdx.x] += red[threadIdx.x + o];
        __syncthreads();
    }
    if (threadIdx.x == 0) out[0] = red[0] / (NN * 32.f);
}

// ---------------- init helpers ----------------
__global__ void build_wcat(const float* __restrict__ W1, const float* __restrict__ Wbil,
                           u16* __restrict__ Wcat)
{
    int idx = blockIdx.x * 256 + threadIdx.x;
    if (idx >= 2304 * DD) return;
    int r = idx / DD, k = idx % DD;
    float v;
    if (r < 768) v = W1[(size_t)r * 1536 + k];
    else if (r < 1536) v = W1[(size_t)(r - 768) * 1536 + 768 + k];
    else v = Wbil[(size_t)(r - 1536) * DD + k];
    Wcat[idx] = f2bf(v);
}

__global__ void cvt_k(const float* __restrict__ in, u16* __restrict__ out, int n)
{
    int idx = blockIdx.x * 256 + threadIdx.x;
    if (idx < n) out[idx] = f2bf(in[idx]);
}

__global__ void init_rootb(u16* __restrict__ ovb, const float* __restrict__ rb)
{
    int idx = blockIdx.x * 256 + threadIdx.x;
    if (idx < 32 * DD) ovb[(size_t)819 * 32 * DD + idx] = f2bf(rb[idx % DD]);
}

extern "C" void kernel_launch(void* const* d_in, const int* in_sizes, int n_in,
                              void* d_out, int out_size, void* d_ws, size_t ws_size,
                              hipStream_t stream)
{
    const float* base  = (const float*)d_in[0];
    const float* Wbil  = (const float*)d_in[1];
    const float* W1    = (const float*)d_in[2];
    const float* b1    = (const float*)d_in[3];
    const float* W2    = (const float*)d_in[4];
    const float* b2    = (const float*)d_in[5];
    const float* rbias = (const float*)d_in[6];
    float* out = (float*)d_out;

    char* ws = (char*)d_ws;
    size_t off = 0;
    auto alloc = [&](size_t bytes) { size_t o = off; off = (off + bytes + 255) & ~(size_t)255; return o; };
    const size_t SB = (size_t)TT * 32 * DD * 2;   // 40.3 MB bf16 per chart slab
    u16*  ivb = (u16*)(ws + alloc(SB));           // raw inside chart; outside-pass v-scratch
    u16*  ovb = (u16*)(ws + alloc(SB));           // raw outside chart
    u16*  Ub  = (u16*)(ws + alloc(SB));           // u = x@W1L^T (inside) / u_o = o@W1L^T (outside reuse)
    u16*  Vb  = (u16*)(ws + alloc(SB));           // v = x@W1R^T (inside cells)
    u16*  IWb = (u16*)(ws + alloc(SB));           // W_bil @ x   (inside cells)
    u16*  Wcat = (u16*)(ws + alloc((size_t)2304 * DD * 2));
    u16*  W2b  = (u16*)(ws + alloc((size_t)DD * DD * 2));
    float* isc = (float*)(ws + alloc((size_t)TT * 32 * 4));
    float* osc = (float*)(ws + alloc((size_t)TT * 32 * 4));
    float* scb = (float*)(ws + alloc((size_t)1560 * 32 * 4));
    float* wb  = (float*)(ws + alloc((size_t)1560 * 32 * 4));
    float* lb  = (float*)(ws + alloc((size_t)NN * 32 * 4));
    u16*  vin  = (u16*)(ws + alloc((size_t)400 * 32 * DD * 2)); // inside v: max nb*S=400

    // --- init ---
    hipMemsetAsync(isc, 0, (size_t)TT * 32 * 4, stream);
    hipMemsetAsync(osc, 0, (size_t)TT * 32 * 4, stream);
    build_wcat<<<(2304 * DD + 255) / 256, 256, 0, stream>>>(W1, Wbil, Wcat);
    cvt_k<<<(DD * DD + 255) / 256, 256, 0, stream>>>(W2, W2b, DD * DD);
    cvt_k<<<(NN * 32 * DD + 255) / 256, 256, 0, stream>>>(base, ivb, NN * 32 * DD);
    init_rootb<<<(32 * DD + 255) / 256, 256, 0, stream>>>(ovb, rbias);
    {   // leaf transforms: U/V/IW for cells 0..39
        int M = NN * 32;
        dim3 g((M + 127) / 128, 18);
        transform_k<<<g, 256, 0, stream>>>(ivb, Wcat, Ub, Vb, IWb, M);
    }

    // --- inside pass (skip L=40: root iv/isc unused downstream) ---
    for (int L = 2; L <= NN - 1; ++L) {
        int S = L - 1, nb = NN + 1 - L;
        int cellbase = TT - (NN - L + 2) * (NN - L + 1) / 2;
        int Pc = nb * S, Mc = Pc * 32;
        score_k<true><<<(Pc * 32 + 3) / 4, 256, 0, stream>>>(
            ivb, IWb, ovb, isc, osc, scb, L, Pc, S);
        softmax_k<<<(nb * 32 + 3) / 4, 256, 0, stream>>>(
            scb, wb, isc, cellbase * 32, nb, S);
        dim3 g1((Mc + 127) / 128, 6);
        gemm2f_k<MODE_IN><<<g1, 256, 0, stream>>>(
            Ub, Vb, W2b, b1, b2, wb, vin, Mc, L, 0, S);
        reduce_k<<<(nb * 32 * DD + 255) / 256, 256, 0, stream>>>(
            vin, ivb, cellbase * 32, nb, S);
        {   // transform the new cells
            int M = nb * 32;
            dim3 g((M + 127) / 128, 18);
            transform_k<<<g, 256, 0, stream>>>(
                ivb + (size_t)cellbase * 32 * DD, Wcat,
                Ub + (size_t)cellbase * 32 * DD, Vb + (size_t)cellbase * 32 * DD,
                IWb + (size_t)cellbase * 32 * DD, M);
        }
    }

    // --- root u_o ---
    {
        dim3 g(1, 6);
        transform_k<<<g, 256, 0, stream>>>(
            ovb + (size_t)819 * 32 * DD, Wcat,
            Ub + (size_t)819 * 32 * DD, nullptr, nullptr, 32);
    }

    // --- outside pass (v-scratch = ivb slab, chunked) ---
    for (int L = NN - 1; L >= 1; --L) {
        int S = NN - L, nb = NN + 1 - L;
        int cellbase = TT - (NN - L + 2) * (NN - L + 1) / 2;
        int Pc = nb * S;
        score_k<false><<<(Pc * 32 + 3) / 4, 256, 0, stream>>>(
            ivb /*unused lp*/, IWb, ovb, isc, osc, scb, L, Pc, S);
        softmax_k<<<(nb * 32 + 3) / 4, 256, 0, stream>>>(
            scb, wb, osc, cellbase * 32, nb, S);
        size_t perbegin = (size_t)S * 32 * DD * 2;
        int GC = (int)(SB / perbegin);
        if (GC < 1) GC = 1;
        if (GC > nb) GC = nb;
        for (int g0 = 0; g0 < nb; g0 += GC) {
            int gc = (g0 + GC <= nb) ? GC : (nb - g0);
            int Mc = gc * S * 32;
            dim3 g1((Mc + 127) / 128, 6);
            gemm2f_k<MODE_OUT><<<g1, 256, 0, stream>>>(
                Ub, Vb, W2b, b1, b2, wb + (size_t)g0 * S * 32,
                ivb, Mc, L, g0, S);
            reduce_k<<<(gc * 32 * DD + 255) / 256, 256, 0, stream>>>(
                ivb, ovb, (cellbase + g0) * 32, gc, S);
        }
        if (L > 1) {   // u_o for the new outside cells (L=1 cells feed only the loss)
            int M = nb * 32;
            dim3 g((M + 127) / 128, 6);
            transform_k<<<g, 256, 0, stream>>>(
                ovb + (size_t)cellbase * 32 * DD, Wcat,
                Ub + (size_t)cellbase * 32 * DD, nullptr, nullptr, M);
        }
    }

    // --- loss ---
    loss_part<<<(NN * 32 + 3) / 4, 256, 0, stream>>>(ovb, base, lb);
    loss_fin<<<1, 256, 0, stream>>>(lb, out);
}